// Round 2
// baseline (364.159 us; speedup 1.0000x reference)
//
#include <hip/hip_runtime.h>
#include <stdint.h>

#define A_DIM 128
#define E_DIM 512
#define NFLT  32
#define KW    31
#define BATCH 64
#define T_DIM 1024

typedef short short8 __attribute__((ext_vector_type(8)));
typedef float float4v __attribute__((ext_vector_type(4)));

__device__ __forceinline__ unsigned short f2bf(float f) {
    union { float f; unsigned int u; } x; x.f = f;
    unsigned int u = x.u;
    return (unsigned short)((u + 0x7fffu + ((u >> 16) & 1u)) >> 16);
}

// ---------------- prep: Wm->bf16, Wl->bf16, pq = hidden @ Wq^T ----------------
__global__ __launch_bounds__(256) void prep_kernel(
    const float* __restrict__ hidden, const float* __restrict__ Wq,
    const float* __restrict__ Wm, const float* __restrict__ Wl,
    unsigned short* __restrict__ Wm_bf, unsigned short* __restrict__ Wl_bf,
    float* __restrict__ pq)
{
    int idx = blockIdx.x * 256 + threadIdx.x;
    if (idx < A_DIM * E_DIM) {
        Wm_bf[idx] = f2bf(Wm[idx]);
    } else if (idx < A_DIM * E_DIM + A_DIM * NFLT) {
        int i = idx - A_DIM * E_DIM;
        Wl_bf[i] = f2bf(Wl[i]);
    } else if (idx < A_DIM * E_DIM + A_DIM * NFLT + BATCH * A_DIM) {
        int i = idx - (A_DIM * E_DIM + A_DIM * NFLT);
        int b = i >> 7, a = i & 127;
        const float* h = hidden + b * A_DIM;
        const float* wq = Wq + a * A_DIM;
        float s = 0.f;
        for (int j = 0; j < A_DIM; ++j) s += h[j] * wq[j];
        pq[i] = s;
    }
}

// ---------------- mask dtype detection ----------------
// Scans first 65536 bytes (= min guaranteed size across interpretations) as u32.
// int32 bool: all values in {0,1}. float32 bool: {0, 0x3F800000}. uint8 bool:
// packed 0/1 bytes -> values like 0x01000100 (never 0x3F800000, not all <=1).
__global__ __launch_bounds__(256) void detect_mask_kernel(
    const unsigned int* __restrict__ mw, int* __restrict__ flag)
{
    __shared__ unsigned int red[256];
    unsigned int f = 0;
    for (int i = threadIdx.x; i < 16384; i += 256) {
        unsigned int v = mw[i];
        if (v == 0x3F800000u) f |= 1u;
        else if (v > 1u) f |= 2u;
    }
    red[threadIdx.x] = f;
    __syncthreads();
    for (int s = 128; s > 0; s >>= 1) {
        if (threadIdx.x < (unsigned)s) red[threadIdx.x] |= red[threadIdx.x + s];
        __syncthreads();
    }
    if (threadIdx.x == 0) {
        unsigned int r = red[0];
        flag[0] = (r & 1u) ? 2 : ((r & 2u) ? 1 : 0);  // 0=int32, 1=uint8, 2=float32
    }
}

// ---------------- energies: Z = P@Wm^T + pa + pq -> tanh -> dot v ----------------
__global__ __launch_bounds__(256) void energies_kernel(
    const float* __restrict__ P,              // processed_memory [B,T,E]
    const float* __restrict__ awcat,          // [B,2,T]
    const float* __restrict__ convw,          // [NFLT,2,KW]
    const unsigned short* __restrict__ Wm_bf, // [A,E] bf16
    const unsigned short* __restrict__ Wl_bf, // [A,NFLT] bf16
    const float* __restrict__ pq,             // [B,A]
    const float* __restrict__ vvec,           // [A]
    float* __restrict__ energies)             // [B,T]
{
    const int tid = threadIdx.x;
    const int b  = blockIdx.x >> 3;
    const int t0 = (blockIdx.x & 7) << 7;

    __shared__ float aw_lds[2][160];
    __shared__ unsigned short loc_lds[128][NFLT];  // [t][f] bf16

    // stage attention_weights_cat slice [t0-15, t0+143)
    for (int i = tid; i < 320; i += 256) {
        int c = i / 160, j = i % 160;
        int tg = t0 - 15 + j;
        float vl = 0.f;
        if (j < 158 && tg >= 0 && tg < T_DIM) vl = awcat[(b * 2 + c) * T_DIM + tg];
        aw_lds[c][j] = vl;
    }
    __syncthreads();

    // conv tile: loc[t][f] = sum_{c,k} aw[c][t+k-15] * convw[f,c,k]
    {
        int f = tid >> 3;
        int s = tid & 7;
        float acc[16];
        #pragma unroll
        for (int i = 0; i < 16; ++i) acc[i] = 0.f;
        for (int c = 0; c < 2; ++c) {
            const float* w = convw + (f * 2 + c) * KW;
            for (int k = 0; k < KW; ++k) {
                float wvv = w[k];
                #pragma unroll
                for (int i = 0; i < 16; ++i)
                    acc[i] += wvv * aw_lds[c][s + 8 * i + k];
            }
        }
        #pragma unroll
        for (int i = 0; i < 16; ++i)
            loc_lds[s + 8 * i][f] = f2bf(acc[i]);
    }
    __syncthreads();

    const int lane = tid & 63;
    const int wv   = tid >> 6;
    const int lr   = lane & 15;    // A-row / B-col / D-col index
    const int lq   = lane >> 4;    // quarter
    const int k8   = lq * 8;

    float pqf[8], vf[8];
    #pragma unroll
    for (int nf = 0; nf < 8; ++nf) {
        pqf[nf] = pq[b * A_DIM + lr + 16 * nf];
        vf[nf]  = vvec[lr + 16 * nf];
    }

    float4v acc[2][8];
    #pragma unroll
    for (int mf = 0; mf < 2; ++mf)
        #pragma unroll
        for (int nf = 0; nf < 8; ++nf)
            acc[mf][nf] = (float4v){0.f, 0.f, 0.f, 0.f};

    // pa GEMM: K=32 (loc as A, Wl as B) folded into accumulator
    {
        short8 aF[2];
        #pragma unroll
        for (int mf = 0; mf < 2; ++mf) {
            int trow = wv * 32 + mf * 16 + lr;
            aF[mf] = *reinterpret_cast<const short8*>(&loc_lds[trow][k8]);
        }
        #pragma unroll
        for (int nf = 0; nf < 8; ++nf) {
            short8 bF = *reinterpret_cast<const short8*>(&Wl_bf[(lr + 16 * nf) * NFLT + k8]);
            #pragma unroll
            for (int mf = 0; mf < 2; ++mf)
                acc[mf][nf] = __builtin_amdgcn_mfma_f32_16x16x32_bf16(aF[mf], bF, acc[mf][nf], 0, 0, 0);
        }
    }

    // main GEMM over E=512: A-frags direct from global f32 (convert), B from bf16 Wm
    const float* Prow[2];
    #pragma unroll
    for (int mf = 0; mf < 2; ++mf) {
        size_t trowg = (size_t)(b * T_DIM + t0 + wv * 32 + mf * 16 + lr);
        Prow[mf] = P + trowg * E_DIM + k8;
    }
    const unsigned short* WmB[8];
    #pragma unroll
    for (int nf = 0; nf < 8; ++nf)
        WmB[nf] = Wm_bf + (size_t)(lr + 16 * nf) * E_DIM + k8;

    #pragma unroll 4
    for (int e0 = 0; e0 < E_DIM; e0 += 32) {
        short8 aF[2];
        #pragma unroll
        for (int mf = 0; mf < 2; ++mf) {
            float4v p0 = *reinterpret_cast<const float4v*>(Prow[mf] + e0);
            float4v p1 = *reinterpret_cast<const float4v*>(Prow[mf] + e0 + 4);
            short8 t;
            #pragma unroll
            for (int j = 0; j < 4; ++j) t[j] = (short)f2bf(p0[j]);
            #pragma unroll
            for (int j = 0; j < 4; ++j) t[4 + j] = (short)f2bf(p1[j]);
            aF[mf] = t;
        }
        #pragma unroll
        for (int nf = 0; nf < 8; ++nf) {
            short8 bF = *reinterpret_cast<const short8*>(WmB[nf] + e0);
            #pragma unroll
            for (int mf = 0; mf < 2; ++mf)
                acc[mf][nf] = __builtin_amdgcn_mfma_f32_16x16x32_bf16(aF[mf], bF, acc[mf][nf], 0, 0, 0);
        }
    }

    // epilogue: tanh + dot(v) + 16-lane reduce
    #pragma unroll
    for (int mf = 0; mf < 2; ++mf) {
        #pragma unroll
        for (int reg = 0; reg < 4; ++reg) {
            float s = 0.f;
            #pragma unroll
            for (int nf = 0; nf < 8; ++nf) {
                float z = acc[mf][nf][reg] + pqf[nf];
                float th = 1.f - 2.f / (1.f + __expf(2.f * z));
                s += th * vf[nf];
            }
            s += __shfl_xor(s, 1);
            s += __shfl_xor(s, 2);
            s += __shfl_xor(s, 4);
            s += __shfl_xor(s, 8);
            if (lr == 0) {
                int t = t0 + wv * 32 + mf * 16 + 4 * lq + reg;
                energies[b * T_DIM + t] = s;
            }
        }
    }
}

// ---------------- masked softmax over T; also zero context region ----------------
__global__ __launch_bounds__(256) void softmax_kernel(
    const float* __restrict__ energies,
    const void* __restrict__ mask,
    const int* __restrict__ mode_flag,
    float* __restrict__ out)  // d_out: [0,32768) ctx, [32768,98304) weights
{
    int b = blockIdx.x, tid = threadIdx.x;
    int mode = mode_flag[0];
    __shared__ float redmax[4];
    __shared__ float redsum[4];
    float x[4];
    #pragma unroll
    for (int i = 0; i < 4; ++i) {
        int idx = b * T_DIM + i * 256 + tid;
        bool msk;
        if (mode == 0)      msk = ((const int*)mask)[idx] != 0;
        else if (mode == 1) msk = ((const unsigned char*)mask)[idx] != 0;
        else                msk = ((const float*)mask)[idx] != 0.f;
        float e = energies[idx];
        x[i] = msk ? -__builtin_inff() : e;
    }
    float m = fmaxf(fmaxf(x[0], x[1]), fmaxf(x[2], x[3]));
    #pragma unroll
    for (int o = 1; o < 64; o <<= 1) m = fmaxf(m, __shfl_xor(m, o));
    if ((tid & 63) == 0) redmax[tid >> 6] = m;
    __syncthreads();
    m = fmaxf(fmaxf(redmax[0], redmax[1]), fmaxf(redmax[2], redmax[3]));

    float p[4], s = 0.f;
    #pragma unroll
    for (int i = 0; i < 4; ++i) { p[i] = __expf(x[i] - m); s += p[i]; }
    #pragma unroll
    for (int o = 1; o < 64; o <<= 1) s += __shfl_xor(s, o);
    if ((tid & 63) == 0) redsum[tid >> 6] = s;
    __syncthreads();
    s = redsum[0] + redsum[1] + redsum[2] + redsum[3];

    float inv = 1.f / s;
    #pragma unroll
    for (int i = 0; i < 4; ++i)
        out[BATCH * E_DIM + b * T_DIM + i * 256 + tid] = p[i] * inv;

    // zero context row for this b (context kernel accumulates atomically after)
    out[b * E_DIM + tid] = 0.f;
    out[b * E_DIM + 256 + tid] = 0.f;
}

// ---------------- context = weights @ memory ----------------
__global__ __launch_bounds__(256) void context_kernel(
    const float* __restrict__ memory,
    const float* __restrict__ weights,  // d_out + 32768
    float* __restrict__ ctx)            // d_out
{
    int b  = blockIdx.x >> 3;
    int t0 = (blockIdx.x & 7) << 7;
    int tid = threadIdx.x;
    __shared__ float wl[128];
    if (tid < 128) wl[tid] = weights[b * T_DIM + t0 + tid];
    __syncthreads();
    const float2* mrow = reinterpret_cast<const float2*>(memory + (size_t)(b * T_DIM + t0) * E_DIM);
    float accx = 0.f, accy = 0.f;
    #pragma unroll 8
    for (int t = 0; t < 128; ++t) {
        float w = wl[t];
        float2 mv = mrow[t * 256 + tid];
        accx += w * mv.x;
        accy += w * mv.y;
    }
    atomicAdd(&ctx[b * E_DIM + 2 * tid], accx);
    atomicAdd(&ctx[b * E_DIM + 2 * tid + 1], accy);
}

extern "C" void kernel_launch(void* const* d_in, const int* in_sizes, int n_in,
                              void* d_out, int out_size, void* d_ws, size_t ws_size,
                              hipStream_t stream) {
    const float* hidden  = (const float*)d_in[0];
    const float* memory  = (const float*)d_in[1];
    const float* procmem = (const float*)d_in[2];
    const float* awcat   = (const float*)d_in[3];
    const void*  mask    = d_in[4];
    const float* Wq      = (const float*)d_in[5];
    const float* Wm      = (const float*)d_in[6];
    const float* v       = (const float*)d_in[7];
    const float* convw   = (const float*)d_in[8];
    const float* Wl      = (const float*)d_in[9];
    float* out = (float*)d_out;

    char* ws = (char*)d_ws;
    float* energies       = (float*)ws;                                      // 262144 B
    float* pq             = (float*)(ws + 262144);                           // 32768 B
    unsigned short* Wm_bf = (unsigned short*)(ws + 262144 + 32768);          // 131072 B
    unsigned short* Wl_bf = (unsigned short*)(ws + 262144 + 32768 + 131072); // 8192 B
    int* mode_flag        = (int*)(ws + 262144 + 32768 + 131072 + 8192);     // 4 B

    prep_kernel<<<304, 256, 0, stream>>>(hidden, Wq, Wm, Wl, Wm_bf, Wl_bf, pq);
    detect_mask_kernel<<<1, 256, 0, stream>>>((const unsigned int*)mask, mode_flag);
    energies_kernel<<<512, 256, 0, stream>>>(procmem, awcat, convw, Wm_bf, Wl_bf, pq, v, energies);
    softmax_kernel<<<64, 256, 0, stream>>>(energies, mask, mode_flag, out);
    context_kernel<<<512, 256, 0, stream>>>(memory, out + BATCH * E_DIM, out);
}

// Round 3
// 354.083 us; speedup vs baseline: 1.0285x; 1.0285x over previous
//
#include <hip/hip_runtime.h>
#include <stdint.h>

#define A_DIM 128
#define E_DIM 512
#define NFLT  32
#define KW    31
#define BATCH 64
#define T_DIM 1024

typedef short short8 __attribute__((ext_vector_type(8)));
typedef float float4v __attribute__((ext_vector_type(4)));

__device__ __forceinline__ unsigned short f2bf(float f) {
    union { float f; unsigned int u; } x; x.f = f;
    unsigned int u = x.u;
    return (unsigned short)((u + 0x7fffu + ((u >> 16) & 1u)) >> 16);
}

// ---------------- prep: Wm->bf16, Wl->bf16, pq = hidden @ Wq^T, + mask detect ----------------
// blocks 0..303: conversion + pq.  block 304: mask dtype detection.
__global__ __launch_bounds__(256) void prep_kernel(
    const float* __restrict__ hidden, const float* __restrict__ Wq,
    const float* __restrict__ Wm, const float* __restrict__ Wl,
    unsigned short* __restrict__ Wm_bf, unsigned short* __restrict__ Wl_bf,
    float* __restrict__ pq,
    const unsigned int* __restrict__ maskw, int* __restrict__ mode_flag)
{
    if (blockIdx.x == 304) {
        // detect mask dtype from first 4KB (1024 u32 words; min alloc = 64KB).
        // int32 bool: all words in {0,1}. float32 bool: some word == 0x3F800000.
        // uint8 bool: packed 0/1 bytes -> words >1, never 0x3F800000.
        __shared__ unsigned int red[256];
        unsigned int f = 0;
        #pragma unroll
        for (int i = 0; i < 4; ++i) {
            unsigned int v = maskw[threadIdx.x + 256 * i];
            if (v == 0x3F800000u) f |= 1u;
            else if (v > 1u) f |= 2u;
        }
        red[threadIdx.x] = f;
        __syncthreads();
        for (int s = 128; s > 0; s >>= 1) {
            if (threadIdx.x < (unsigned)s) red[threadIdx.x] |= red[threadIdx.x + s];
            __syncthreads();
        }
        if (threadIdx.x == 0) {
            unsigned int r = red[0];
            mode_flag[0] = (r & 1u) ? 2 : ((r & 2u) ? 1 : 0);  // 0=int32,1=uint8,2=float32
        }
        return;
    }
    int idx = blockIdx.x * 256 + threadIdx.x;
    if (idx < A_DIM * E_DIM) {
        Wm_bf[idx] = f2bf(Wm[idx]);
    } else if (idx < A_DIM * E_DIM + A_DIM * NFLT) {
        int i = idx - A_DIM * E_DIM;
        Wl_bf[i] = f2bf(Wl[i]);
    } else if (idx < A_DIM * E_DIM + A_DIM * NFLT + BATCH * A_DIM) {
        int i = idx - (A_DIM * E_DIM + A_DIM * NFLT);
        int b = i >> 7, a = i & 127;
        const float* h = hidden + b * A_DIM;
        const float* wq = Wq + a * A_DIM;
        float s = 0.f;
        for (int j = 0; j < A_DIM; ++j) s += h[j] * wq[j];
        pq[i] = s;
    }
}

// ---------------- energies: Z = P@Wm^T + pa + pq -> tanh -> dot v ----------------
// 1024 blocks: b = blk>>4, t-tile of 64 rows. 4 waves x 16 rows each.
__global__ __launch_bounds__(256, 4) void energies_kernel(
    const float* __restrict__ P,              // processed_memory [B,T,E]
    const float* __restrict__ awcat,          // [B,2,T]
    const float* __restrict__ convw,          // [NFLT,2,KW]
    const unsigned short* __restrict__ Wm_bf, // [A,E] bf16
    const unsigned short* __restrict__ Wl_bf, // [A,NFLT] bf16
    const float* __restrict__ pq,             // [B,A]
    const float* __restrict__ vvec,           // [A]
    float* __restrict__ energies)             // [B,T]
{
    const int tid = threadIdx.x;
    const int b  = blockIdx.x >> 4;
    const int t0 = (blockIdx.x & 15) << 6;

    __shared__ float aw_lds[2][96];
    __shared__ unsigned short loc_lds[64][NFLT];  // [t][f] bf16

    // stage attention_weights_cat slice [t0-15, t0+79)
    for (int i = tid; i < 192; i += 256) {
        int c = i / 96, j = i % 96;
        int tg = t0 - 15 + j;
        float vl = 0.f;
        if (j < 94 && tg >= 0 && tg < T_DIM) vl = awcat[(b * 2 + c) * T_DIM + tg];
        aw_lds[c][j] = vl;
    }
    __syncthreads();

    // conv tile: loc[t][f] = sum_{c,k} aw[c][t+k] * convw[f,c,k]   (t local)
    {
        int f = tid >> 3;
        int s = tid & 7;
        float acc[8];
        #pragma unroll
        for (int i = 0; i < 8; ++i) acc[i] = 0.f;
        for (int c = 0; c < 2; ++c) {
            const float* w = convw + (f * 2 + c) * KW;
            for (int k = 0; k < KW; ++k) {
                float wvv = w[k];
                #pragma unroll
                for (int i = 0; i < 8; ++i)
                    acc[i] += wvv * aw_lds[c][s + 8 * i + k];
            }
        }
        #pragma unroll
        for (int i = 0; i < 8; ++i)
            loc_lds[s + 8 * i][f] = f2bf(acc[i]);
    }
    __syncthreads();

    const int lane = tid & 63;
    const int wv   = tid >> 6;
    const int lr   = lane & 15;    // A-row / B-col / D-col index
    const int lq   = lane >> 4;    // quarter
    const int k8   = lq * 8;
    const int row  = wv * 16 + lr; // local t-row this lane's A-frag reads

    float pqf[8], vf[8];
    #pragma unroll
    for (int nf = 0; nf < 8; ++nf) {
        pqf[nf] = pq[b * A_DIM + lr + 16 * nf];
        vf[nf]  = vvec[lr + 16 * nf];
    }

    float4v acc[8];
    #pragma unroll
    for (int nf = 0; nf < 8; ++nf)
        acc[nf] = (float4v){0.f, 0.f, 0.f, 0.f};

    // pa GEMM: K=32 (loc as A, Wl as B) folded into accumulator
    {
        short8 aF = *reinterpret_cast<const short8*>(&loc_lds[row][k8]);
        #pragma unroll
        for (int nf = 0; nf < 8; ++nf) {
            short8 bF = *reinterpret_cast<const short8*>(&Wl_bf[(lr + 16 * nf) * NFLT + k8]);
            acc[nf] = __builtin_amdgcn_mfma_f32_16x16x32_bf16(aF, bF, acc[nf], 0, 0, 0);
        }
    }

    // main GEMM over E=512: A-frags direct from global f32 (convert), B from bf16 Wm
    const float* Prow = P + (size_t)(b * T_DIM + t0 + row) * E_DIM + k8;
    const unsigned short* WmB[8];
    #pragma unroll
    for (int nf = 0; nf < 8; ++nf)
        WmB[nf] = Wm_bf + (size_t)(lr + 16 * nf) * E_DIM + k8;

    #pragma unroll 4
    for (int e0 = 0; e0 < E_DIM; e0 += 32) {
        float4v p0 = *reinterpret_cast<const float4v*>(Prow + e0);
        float4v p1 = *reinterpret_cast<const float4v*>(Prow + e0 + 4);
        short8 aF;
        #pragma unroll
        for (int j = 0; j < 4; ++j) aF[j] = (short)f2bf(p0[j]);
        #pragma unroll
        for (int j = 0; j < 4; ++j) aF[4 + j] = (short)f2bf(p1[j]);
        #pragma unroll
        for (int nf = 0; nf < 8; ++nf) {
            short8 bF = *reinterpret_cast<const short8*>(WmB[nf] + e0);
            acc[nf] = __builtin_amdgcn_mfma_f32_16x16x32_bf16(aF, bF, acc[nf], 0, 0, 0);
        }
    }

    // epilogue: tanh + dot(v) + 16-lane reduce
    #pragma unroll
    for (int reg = 0; reg < 4; ++reg) {
        float s = 0.f;
        #pragma unroll
        for (int nf = 0; nf < 8; ++nf) {
            float z = acc[nf][reg] + pqf[nf];
            float th = 1.f - 2.f / (1.f + __expf(2.f * z));
            s += th * vf[nf];
        }
        s += __shfl_xor(s, 1);
        s += __shfl_xor(s, 2);
        s += __shfl_xor(s, 4);
        s += __shfl_xor(s, 8);
        if (lr == 0) {
            int t = t0 + wv * 16 + 4 * lq + reg;
            energies[b * T_DIM + t] = s;
        }
    }
}

// ---------------- masked softmax over T; also zero context region ----------------
__global__ __launch_bounds__(256) void softmax_kernel(
    const float* __restrict__ energies,
    const void* __restrict__ mask,
    const int* __restrict__ mode_flag,
    float* __restrict__ out)  // d_out: [0,32768) ctx, [32768,98304) weights
{
    int b = blockIdx.x, tid = threadIdx.x;
    int mode = mode_flag[0];
    __shared__ float redmax[4];
    __shared__ float redsum[4];
    float x[4];
    #pragma unroll
    for (int i = 0; i < 4; ++i) {
        int idx = b * T_DIM + i * 256 + tid;
        bool msk;
        if (mode == 0)      msk = ((const int*)mask)[idx] != 0;
        else if (mode == 1) msk = ((const unsigned char*)mask)[idx] != 0;
        else                msk = ((const float*)mask)[idx] != 0.f;
        float e = energies[idx];
        x[i] = msk ? -__builtin_inff() : e;
    }
    float m = fmaxf(fmaxf(x[0], x[1]), fmaxf(x[2], x[3]));
    #pragma unroll
    for (int o = 1; o < 64; o <<= 1) m = fmaxf(m, __shfl_xor(m, o));
    if ((tid & 63) == 0) redmax[tid >> 6] = m;
    __syncthreads();
    m = fmaxf(fmaxf(redmax[0], redmax[1]), fmaxf(redmax[2], redmax[3]));

    float p[4], s = 0.f;
    #pragma unroll
    for (int i = 0; i < 4; ++i) { p[i] = __expf(x[i] - m); s += p[i]; }
    #pragma unroll
    for (int o = 1; o < 64; o <<= 1) s += __shfl_xor(s, o);
    if ((tid & 63) == 0) redsum[tid >> 6] = s;
    __syncthreads();
    s = redsum[0] + redsum[1] + redsum[2] + redsum[3];

    float inv = 1.f / s;
    #pragma unroll
    for (int i = 0; i < 4; ++i)
        out[BATCH * E_DIM + b * T_DIM + i * 256 + tid] = p[i] * inv;

    // zero context row for this b (context kernel accumulates atomically after)
    out[b * E_DIM + tid] = 0.f;
    out[b * E_DIM + 256 + tid] = 0.f;
}

// ---------------- context = weights @ memory ----------------
// 2048 blocks: b = blk>>5, 32-t chunk. float2 per lane, atomic combine.
__global__ __launch_bounds__(256) void context_kernel(
    const float* __restrict__ memory,
    const float* __restrict__ weights,  // d_out + 32768
    float* __restrict__ ctx)            // d_out
{
    int b  = blockIdx.x >> 5;
    int t0 = (blockIdx.x & 31) << 5;
    int tid = threadIdx.x;
    __shared__ float wl[32];
    if (tid < 32) wl[tid] = weights[b * T_DIM + t0 + tid];
    __syncthreads();
    const float2* mrow = reinterpret_cast<const float2*>(memory + (size_t)(b * T_DIM + t0) * E_DIM);
    float accx = 0.f, accy = 0.f;
    #pragma unroll 8
    for (int t = 0; t < 32; ++t) {
        float w = wl[t];
        float2 mv = mrow[t * 256 + tid];
        accx += w * mv.x;
        accy += w * mv.y;
    }
    atomicAdd(&ctx[b * E_DIM + 2 * tid], accx);
    atomicAdd(&ctx[b * E_DIM + 2 * tid + 1], accy);
}

extern "C" void kernel_launch(void* const* d_in, const int* in_sizes, int n_in,
                              void* d_out, int out_size, void* d_ws, size_t ws_size,
                              hipStream_t stream) {
    const float* hidden  = (const float*)d_in[0];
    const float* memory  = (const float*)d_in[1];
    const float* procmem = (const float*)d_in[2];
    const float* awcat   = (const float*)d_in[3];
    const void*  mask    = d_in[4];
    const float* Wq      = (const float*)d_in[5];
    const float* Wm      = (const float*)d_in[6];
    const float* v       = (const float*)d_in[7];
    const float* convw   = (const float*)d_in[8];
    const float* Wl      = (const float*)d_in[9];
    float* out = (float*)d_out;

    char* ws = (char*)d_ws;
    float* energies       = (float*)ws;                                      // 262144 B
    float* pq             = (float*)(ws + 262144);                           // 32768 B
    unsigned short* Wm_bf = (unsigned short*)(ws + 262144 + 32768);          // 131072 B
    unsigned short* Wl_bf = (unsigned short*)(ws + 262144 + 32768 + 131072); // 8192 B
    int* mode_flag        = (int*)(ws + 262144 + 32768 + 131072 + 8192);     // 4 B

    prep_kernel<<<305, 256, 0, stream>>>(hidden, Wq, Wm, Wl, Wm_bf, Wl_bf, pq,
                                         (const unsigned int*)mask, mode_flag);
    energies_kernel<<<1024, 256, 0, stream>>>(procmem, awcat, convw, Wm_bf, Wl_bf, pq, v, energies);
    softmax_kernel<<<64, 256, 0, stream>>>(energies, mask, mode_flag, out);
    context_kernel<<<2048, 256, 0, stream>>>(memory, out + BATCH * E_DIM, out);
}